// Round 4
// baseline (176.245 us; speedup 1.0000x reference)
//
#include <hip/hip_runtime.h>
#include <math.h>

#define DIM 512
#define NH 8
#define HD 64
#define SS 2048
#define NB 2

typedef __bf16 bf16;
typedef __attribute__((ext_vector_type(8))) __bf16 bf16x8;
typedef __attribute__((ext_vector_type(4))) float f32x4;

// convert 8 consecutive floats -> bf16x8
__device__ inline bf16x8 cvt8(const float* s) {
  bf16x8 o;
#pragma unroll
  for (int i = 0; i < 8; ++i) o[i] = (bf16)s[i];
  return o;
}

// ---------------------------------------------------------------------------
// K1: QKV projection, bf16 MFMA, T14 prefetch.  y = x@W^T + b -> bf16 [B,H,S,HD].
// q output pre-scaled by 0.125. Tile 128x64, BK=64, 4 waves (2x2).
// ---------------------------------------------------------------------------
__global__ __launch_bounds__(256) void qkv_proj_kernel(
    const float* __restrict__ xq, const float* __restrict__ xk, const float* __restrict__ xv,
    const float* __restrict__ Wq, const float* __restrict__ bq,
    const float* __restrict__ Wk, const float* __restrict__ bk,
    const float* __restrict__ Wv, const float* __restrict__ bv,
    bf16* __restrict__ qh, bf16* __restrict__ kh, bf16* __restrict__ vh)
{
  const int which = blockIdx.z;
  const float* A    = (which == 0) ? xq : (which == 1) ? xk : xv;
  const float* W    = (which == 0) ? Wq : (which == 1) ? Wk : Wv;
  const float* bias = (which == 0) ? bq : (which == 1) ? bk : bv;
  bf16* out         = (which == 0) ? qh : (which == 1) ? kh : vh;
  const float oscale = (which == 0) ? 0.125f : 1.0f;

  __shared__ bf16 As[128][72];
  __shared__ bf16 Bs[64][72];

  const int m0 = blockIdx.x * 128;
  const int n0 = blockIdx.y * 64;
  const int tid = threadIdx.x;
  const int w = tid >> 6, l = tid & 63;
  const int l16 = l & 15, lg = l >> 4;
  const int wm = w >> 1, wn = w & 1;
  const int r = tid >> 1, hf = (tid & 1) * 32;

  f32x4 acc[4][2];
#pragma unroll
  for (int mf = 0; mf < 4; ++mf)
#pragma unroll
    for (int nf = 0; nf < 2; ++nf) acc[mf][nf] = (f32x4){0.f, 0.f, 0.f, 0.f};

  bf16x8 aPre[4], bPre[4];
  // prologue: stage k0 = 0
  {
    const float* srcA = &A[(size_t)(m0 + r) * DIM + hf];
#pragma unroll
    for (int i = 0; i < 4; ++i) aPre[i] = cvt8(srcA + i * 8);
    if (tid < 128) {
      const float* srcB = &W[(size_t)(n0 + r) * DIM + hf];
#pragma unroll
      for (int i = 0; i < 4; ++i) bPre[i] = cvt8(srcB + i * 8);
    }
    bf16* dstA = &As[r][hf];
#pragma unroll
    for (int i = 0; i < 4; ++i) ((bf16x8*)dstA)[i] = aPre[i];
    if (tid < 128) {
      bf16* dstB = &Bs[r][hf];
#pragma unroll
      for (int i = 0; i < 4; ++i) ((bf16x8*)dstB)[i] = bPre[i];
    }
  }
  __syncthreads();

  for (int k0 = 0; k0 < DIM; k0 += 64) {
    const int kn = k0 + 64;
    if (kn < DIM) {  // prefetch next K-slab to regs
      const float* srcA = &A[(size_t)(m0 + r) * DIM + kn + hf];
#pragma unroll
      for (int i = 0; i < 4; ++i) aPre[i] = cvt8(srcA + i * 8);
      if (tid < 128) {
        const float* srcB = &W[(size_t)(n0 + r) * DIM + kn + hf];
#pragma unroll
        for (int i = 0; i < 4; ++i) bPre[i] = cvt8(srcB + i * 8);
      }
    }
#pragma unroll
    for (int kk = 0; kk < 2; ++kk) {
      bf16x8 bfr[2];
      bfr[0] = *(const bf16x8*)&Bs[wn * 32 + l16][kk * 32 + lg * 8];
      bfr[1] = *(const bf16x8*)&Bs[wn * 32 + 16 + l16][kk * 32 + lg * 8];
#pragma unroll
      for (int mf = 0; mf < 4; ++mf) {
        const bf16x8 af = *(const bf16x8*)&As[wm * 64 + mf * 16 + l16][kk * 32 + lg * 8];
        acc[mf][0] = __builtin_amdgcn_mfma_f32_16x16x32_bf16(af, bfr[0], acc[mf][0], 0, 0, 0);
        acc[mf][1] = __builtin_amdgcn_mfma_f32_16x16x32_bf16(af, bfr[1], acc[mf][1], 0, 0, 0);
      }
    }
    __syncthreads();
    if (kn < DIM) {
      bf16* dstA = &As[r][hf];
#pragma unroll
      for (int i = 0; i < 4; ++i) ((bf16x8*)dstA)[i] = aPre[i];
      if (tid < 128) {
        bf16* dstB = &Bs[r][hf];
#pragma unroll
        for (int i = 0; i < 4; ++i) ((bf16x8*)dstB)[i] = bPre[i];
      }
    }
    __syncthreads();
  }

  const int h = blockIdx.y;
#pragma unroll
  for (int mf = 0; mf < 4; ++mf) {
#pragma unroll
    for (int nf = 0; nf < 2; ++nf) {
      const int d = wn * 32 + nf * 16 + l16;
#pragma unroll
      for (int ri = 0; ri < 4; ++ri) {
        const int row = m0 + wm * 64 + mf * 16 + lg * 4 + ri;
        const int b = row >> 11, s = row & 2047;
        out[((size_t)(b * NH + h) * SS + s) * HD + d] =
            (bf16)((acc[mf][nf][ri] + bias[n0 + d]) * oscale);
      }
    }
  }
}

// ---------------------------------------------------------------------------
// K2: MFMA flash attention, two-pass. T14 prefetch, swizzled Vt, nt attn store.
// Vt layout: Vt[d*128 + ((chunk ^ (d&7))<<3) + i] = V[chunk*8 + i][d]  (chunk=t/8)
// ---------------------------------------------------------------------------
__global__ __launch_bounds__(256) void attn_kernel(
    const bf16* __restrict__ qh, const bf16* __restrict__ kh, const bf16* __restrict__ vh,
    float* __restrict__ attn, bf16* __restrict__ ctx)
{
  __shared__ bf16 Ks[128][72];     // padded, reg-staged
  __shared__ bf16 Vt[64 * 128];    // XOR-swizzled transpose, 16 KiB
  __shared__ bf16 Ps[4][16][136];  // per-wave P transpose

  const int bh = blockIdx.y;
  const int q0 = blockIdx.x * 64;
  const int tid = threadIdx.x;
  const int w   = tid >> 6;
  const int l   = tid & 63;
  const int l16 = l & 15;
  const int lg  = l >> 4;

  const bf16* qp = qh + (size_t)bh * SS * HD;
  const bf16* kp = kh + (size_t)bh * SS * HD;
  const bf16* vp = vh + (size_t)bh * SS * HD;

  const int qrow = q0 + w * 16 + l16;
  const bf16x8 qf0 = *(const bf16x8*)&qp[(size_t)qrow * HD + lg * 8];
  const bf16x8 qf1 = *(const bf16x8*)&qp[(size_t)qrow * HD + 32 + lg * 8];

  float m_run[4], l_run[4];
#pragma unroll
  for (int rr = 0; rr < 4; ++rr) { m_run[rr] = -1e30f; l_run[rr] = 0.f; }

  // ---------------- pass 1: row max & sum ----------------
  const int r2 = tid >> 1, hh = (tid & 1) * 32;   // K staging: half-row per thread
  {  // prologue: stage tile 0
    const bf16* src = &kp[(size_t)r2 * HD + hh];
    bf16* dst = &Ks[r2][hh];
#pragma unroll
    for (int i = 0; i < 4; ++i) ((bf16x8*)dst)[i] = ((const bf16x8*)src)[i];
  }
  __syncthreads();

  bf16x8 kPre[4];
  for (int t0 = 0; t0 < SS; t0 += 128) {
    const int tn = t0 + 128;
    if (tn < SS) {
      const bf16* src = &kp[(size_t)(tn + r2) * HD + hh];
#pragma unroll
      for (int i = 0; i < 4; ++i) kPre[i] = ((const bf16x8*)src)[i];
    }

    f32x4 accS[8];
#pragma unroll
    for (int n = 0; n < 8; ++n) {
      const bf16x8 kf0 = *(const bf16x8*)&Ks[n * 16 + l16][lg * 8];
      const bf16x8 kf1 = *(const bf16x8*)&Ks[n * 16 + l16][32 + lg * 8];
      f32x4 a = {0.f, 0.f, 0.f, 0.f};
      a = __builtin_amdgcn_mfma_f32_16x16x32_bf16(qf0, kf0, a, 0, 0, 0);
      a = __builtin_amdgcn_mfma_f32_16x16x32_bf16(qf1, kf1, a, 0, 0, 0);
      accS[n] = a;
    }
#pragma unroll
    for (int rr = 0; rr < 4; ++rr) {
      float tmax = accS[0][rr];
#pragma unroll
      for (int n = 1; n < 8; ++n) tmax = fmaxf(tmax, accS[n][rr]);
      const float nm = fmaxf(m_run[rr], tmax);
      float sum = 0.f;
#pragma unroll
      for (int n = 0; n < 8; ++n) sum += __expf(accS[n][rr] - nm);
      l_run[rr] = l_run[rr] * __expf(m_run[rr] - nm) + sum;
      m_run[rr] = nm;
    }
    __syncthreads();
    if (tn < SS) {
      bf16* dst = &Ks[r2][hh];
#pragma unroll
      for (int i = 0; i < 4; ++i) ((bf16x8*)dst)[i] = kPre[i];
    }
    __syncthreads();
  }

#pragma unroll
  for (int rr = 0; rr < 4; ++rr) {
    float m = m_run[rr], ls = l_run[rr];
#pragma unroll
    for (int off = 1; off < 16; off <<= 1) {
      const float m2 = __shfl_xor(m, off);
      const float l2 = __shfl_xor(ls, off);
      const float nm = fmaxf(m, m2);
      ls = ls * __expf(m - nm) + l2 * __expf(m2 - nm);
      m = nm;
    }
    m_run[rr] = m;
    l_run[rr] = 1.f / ls;
  }

  // ---------------- pass 2: P write + P.V ----------------
  f32x4 accC[4];
#pragma unroll
  for (int dt = 0; dt < 4; ++dt) accC[dt] = (f32x4){0.f, 0.f, 0.f, 0.f};

  float* arow_base = attn + ((size_t)(bh * SS + q0 + w * 16)) * SS;

  const bool isV = (tid < 128);
  const int vdb = (tid & 127) >> 4;   // d-block 0..7
  const int vtb = tid & 15;           // t-block 0..15
  const int kr  = tid & 127;          // K row

  {  // prologue: stage tile 0 (K + V)
    if (isV) {
      bf16x8 vr[8];
#pragma unroll
      for (int i = 0; i < 8; ++i)
        vr[i] = *(const bf16x8*)&vp[(size_t)(vtb * 8 + i) * HD + vdb * 8];
#pragma unroll
      for (int j = 0; j < 8; ++j) {
        bf16x8 o;
#pragma unroll
        for (int i = 0; i < 8; ++i) o[i] = vr[i][j];
        *(bf16x8*)&Vt[(vdb * 8 + j) * 128 + ((vtb ^ j) << 3)] = o;
      }
    } else {
      const bf16* src = &kp[(size_t)kr * HD];
      bf16* dst = &Ks[kr][0];
#pragma unroll
      for (int i = 0; i < 8; ++i) ((bf16x8*)dst)[i] = ((const bf16x8*)src)[i];
    }
  }
  __syncthreads();

  bf16x8 pre[8];
  for (int t0 = 0; t0 < SS; t0 += 128) {
    const int tn = t0 + 128;
    if (tn < SS) {
      if (isV) {
#pragma unroll
        for (int i = 0; i < 8; ++i)
          pre[i] = *(const bf16x8*)&vp[(size_t)(tn + vtb * 8 + i) * HD + vdb * 8];
      } else {
        const bf16* src = &kp[(size_t)(tn + kr) * HD];
#pragma unroll
        for (int i = 0; i < 8; ++i) pre[i] = ((const bf16x8*)src)[i];
      }
    }

    f32x4 accS[8];
#pragma unroll
    for (int n = 0; n < 8; ++n) {
      const bf16x8 kf0 = *(const bf16x8*)&Ks[n * 16 + l16][lg * 8];
      const bf16x8 kf1 = *(const bf16x8*)&Ks[n * 16 + l16][32 + lg * 8];
      f32x4 a = {0.f, 0.f, 0.f, 0.f};
      a = __builtin_amdgcn_mfma_f32_16x16x32_bf16(qf0, kf0, a, 0, 0, 0);
      a = __builtin_amdgcn_mfma_f32_16x16x32_bf16(qf1, kf1, a, 0, 0, 0);
      accS[n] = a;
    }

#pragma unroll
    for (int n = 0; n < 8; ++n) {
#pragma unroll
      for (int rr = 0; rr < 4; ++rr) {
        const int row = lg * 4 + rr;
        const float p = __expf(accS[n][rr] - m_run[rr]) * l_run[rr];
        __builtin_nontemporal_store(p, &arow_base[(size_t)row * SS + t0 + n * 16 + l16]);
        Ps[w][row][n * 16 + l16] = (bf16)p;
      }
    }

#pragma unroll
    for (int ts = 0; ts < 4; ++ts) {
      const bf16x8 pa = *(const bf16x8*)&Ps[w][l16][ts * 32 + lg * 8];
#pragma unroll
      for (int dt = 0; dt < 4; ++dt) {
        const int d = dt * 16 + l16;
        const bf16x8 vb = *(const bf16x8*)&Vt[d * 128 + (((ts * 4 + lg) ^ (l16 & 7)) << 3)];
        accC[dt] = __builtin_amdgcn_mfma_f32_16x16x32_bf16(pa, vb, accC[dt], 0, 0, 0);
      }
    }
    __syncthreads();
    if (tn < SS) {
      if (isV) {
#pragma unroll
        for (int j = 0; j < 8; ++j) {
          bf16x8 o;
#pragma unroll
          for (int i = 0; i < 8; ++i) o[i] = pre[i][j];
          *(bf16x8*)&Vt[(vdb * 8 + j) * 128 + ((vtb ^ j) << 3)] = o;
        }
      } else {
        bf16* dst = &Ks[kr][0];
#pragma unroll
        for (int i = 0; i < 8; ++i) ((bf16x8*)dst)[i] = pre[i];
      }
    }
    __syncthreads();
  }

  const int b = bh >> 3, h = bh & 7;
#pragma unroll
  for (int dt = 0; dt < 4; ++dt)
#pragma unroll
    for (int rr = 0; rr < 4; ++rr) {
      const int s = q0 + w * 16 + lg * 4 + rr;
      ctx[((size_t)b * SS + s) * DIM + h * HD + dt * 16 + l16] = (bf16)accC[dt][rr];
    }
}

// ---------------------------------------------------------------------------
// K3: output projection, bf16 MFMA, T14 prefetch. out = ctx @ Wo^T + bo (fp32).
// ---------------------------------------------------------------------------
__global__ __launch_bounds__(256) void out_proj_kernel(
    const bf16* __restrict__ ctx, const float* __restrict__ Wo, const float* __restrict__ bo,
    float* __restrict__ out)
{
  __shared__ bf16 As[128][72];
  __shared__ bf16 Bs[64][72];

  const int m0 = blockIdx.x * 128;
  const int n0 = blockIdx.y * 64;
  const int tid = threadIdx.x;
  const int w = tid >> 6, l = tid & 63;
  const int l16 = l & 15, lg = l >> 4;
  const int wm = w >> 1, wn = w & 1;
  const int r = tid >> 1, hf = (tid & 1) * 32;

  f32x4 acc[4][2];
#pragma unroll
  for (int mf = 0; mf < 4; ++mf)
#pragma unroll
    for (int nf = 0; nf < 2; ++nf) acc[mf][nf] = (f32x4){0.f, 0.f, 0.f, 0.f};

  bf16x8 aPre[4], bPre[4];
  {
    const bf16* srcA = &ctx[(size_t)(m0 + r) * DIM + hf];
#pragma unroll
    for (int i = 0; i < 4; ++i) aPre[i] = ((const bf16x8*)srcA)[i];
    if (tid < 128) {
      const float* srcB = &Wo[(size_t)(n0 + r) * DIM + hf];
#pragma unroll
      for (int i = 0; i < 4; ++i) bPre[i] = cvt8(srcB + i * 8);
    }
    bf16* dstA = &As[r][hf];
#pragma unroll
    for (int i = 0; i < 4; ++i) ((bf16x8*)dstA)[i] = aPre[i];
    if (tid < 128) {
      bf16* dstB = &Bs[r][hf];
#pragma unroll
      for (int i = 0; i < 4; ++i) ((bf16x8*)dstB)[i] = bPre[i];
    }
  }
  __syncthreads();

  for (int k0 = 0; k0 < DIM; k0 += 64) {
    const int kn = k0 + 64;
    if (kn < DIM) {
      const bf16* srcA = &ctx[(size_t)(m0 + r) * DIM + kn + hf];
#pragma unroll
      for (int i = 0; i < 4; ++i) aPre[i] = ((const bf16x8*)srcA)[i];
      if (tid < 128) {
        const float* srcB = &Wo[(size_t)(n0 + r) * DIM + kn + hf];
#pragma unroll
        for (int i = 0; i < 4; ++i) bPre[i] = cvt8(srcB + i * 8);
      }
    }
#pragma unroll
    for (int kk = 0; kk < 2; ++kk) {
      bf16x8 bfr[2];
      bfr[0] = *(const bf16x8*)&Bs[wn * 32 + l16][kk * 32 + lg * 8];
      bfr[1] = *(const bf16x8*)&Bs[wn * 32 + 16 + l16][kk * 32 + lg * 8];
#pragma unroll
      for (int mf = 0; mf < 4; ++mf) {
        const bf16x8 af = *(const bf16x8*)&As[wm * 64 + mf * 16 + l16][kk * 32 + lg * 8];
        acc[mf][0] = __builtin_amdgcn_mfma_f32_16x16x32_bf16(af, bfr[0], acc[mf][0], 0, 0, 0);
        acc[mf][1] = __builtin_amdgcn_mfma_f32_16x16x32_bf16(af, bfr[1], acc[mf][1], 0, 0, 0);
      }
    }
    __syncthreads();
    if (kn < DIM) {
      bf16* dstA = &As[r][hf];
#pragma unroll
      for (int i = 0; i < 4; ++i) ((bf16x8*)dstA)[i] = aPre[i];
      if (tid < 128) {
        bf16* dstB = &Bs[r][hf];
#pragma unroll
        for (int i = 0; i < 4; ++i) ((bf16x8*)dstB)[i] = bPre[i];
      }
    }
    __syncthreads();
  }

#pragma unroll
  for (int mf = 0; mf < 4; ++mf) {
#pragma unroll
    for (int nf = 0; nf < 2; ++nf) {
      const int c = n0 + wn * 32 + nf * 16 + l16;
#pragma unroll
      for (int ri = 0; ri < 4; ++ri) {
        const int row = m0 + wm * 64 + mf * 16 + lg * 4 + ri;
        out[(size_t)row * DIM + c] = acc[mf][nf][ri] + bo[c];
      }
    }
  }
}

// ---------------------------------------------------------------------------
extern "C" void kernel_launch(void* const* d_in, const int* in_sizes, int n_in,
                              void* d_out, int out_size, void* d_ws, size_t ws_size,
                              hipStream_t stream) {
  const float* q  = (const float*)d_in[0];
  const float* k  = (const float*)d_in[1];
  const float* v  = (const float*)d_in[2];
  const float* Wq = (const float*)d_in[3];
  const float* bq = (const float*)d_in[4];
  const float* Wk = (const float*)d_in[5];
  const float* bk = (const float*)d_in[6];
  const float* Wv = (const float*)d_in[7];
  const float* bv = (const float*)d_in[8];
  const float* Wo = (const float*)d_in[9];
  const float* bo = (const float*)d_in[10];

  float* out0 = (float*)d_out;                     // [2,2048,512] fp32
  float* attn = out0 + (size_t)NB * SS * DIM;      // [2,8,2048,2048] fp32

  const size_t HSZ = (size_t)NB * NH * SS * HD;
  bf16* qh  = (bf16*)d_ws;
  bf16* kh  = qh + HSZ;
  bf16* vh  = kh + HSZ;
  bf16* ctx = vh + HSZ;                            // bf16 flat [B,S,DIM]

  dim3 g1(NB * SS / 128, DIM / 64, 3);
  qkv_proj_kernel<<<g1, 256, 0, stream>>>(q, k, v, Wq, bq, Wk, bk, Wv, bv, qh, kh, vh);

  dim3 g2(SS / 64, NB * NH);
  attn_kernel<<<g2, 256, 0, stream>>>(qh, kh, vh, attn, ctx);

  dim3 g3(NB * SS / 128, DIM / 64);
  out_proj_kernel<<<g3, 256, 0, stream>>>(ctx, Wo, bo, out0);
}